// Round 3
// baseline (784.719 us; speedup 1.0000x reference)
//
#include <hip/hip_runtime.h>
#include <cstddef>
#include <cstdint>

#define NE 2048
#define NX 3
#define NROWS (NE - 1)               // rows solved by back-substitution: i = 0..2046
#define BS 64                        // block size (rows per block)
#define BR (3 * BS)                  // 192
#define NBLK 32                      // blocks
#define NCH 8                        // K-staging chunks in k_tinv
#define CHS 8                        // steps per chunk (NCH*CHS == BS)
#define CHQ (CHS * 9 * BS)           // 4608 floats per chunk
#define PERTH (CHQ / 256)            // 18 floats per thread

// ws layout (floats):
//   wf  [3*NE]        @ 0          wf[p][j] = w_j * F[p][j]
//   acc [3*NE]        @ 3*NE       running RHS accumulator
//   Gt  [NBLK*BR*BR]  @ 6*NE       per-block T^{-1}, TRANSPOSED: Gt[b][col][row]
//   cnt [NBLK] ints   @ end        per-stage done-counters (zeroed by k_init)

static __device__ __forceinline__ float dy_of(const float* E) {
    return logf(E[NE - 1] / E[0]) / (float)(NE - 1);
}

__global__ void k_init(const float* __restrict__ E, const float* __restrict__ R,
                       const float* __restrict__ K, const float* __restrict__ S0,
                       const float* __restrict__ SC,
                       float* __restrict__ out, float* __restrict__ wf,
                       float* __restrict__ acc, int* __restrict__ cnt) {
    int i = blockIdx.x * blockDim.x + threadIdx.x;
    if (blockIdx.x == 0 && threadIdx.x < NBLK) cnt[threadIdx.x] = 0;
    if (i >= NE) return;
    const size_t PL = (size_t)NE * NE;
    float dy = dy_of(E);
    float wlast = 0.5f * dy * E[NE - 1];
    float srcl[NX], Fl[NX];
#pragma unroll
    for (int p = 0; p < NX; ++p) srcl[p] = S0[p] / R[p * NE + NE - 1];
#pragma unroll
    for (int x = 0; x < NX; ++x) {
        float s = SC[x * NE + NE - 1];
#pragma unroll
        for (int p = 0; p < NX; ++p)
            s += K[(size_t)(x * NX + p) * PL + (size_t)(NE - 1) * NE + (NE - 1)] * srcl[p];
        Fl[x] = s / R[x * NE + NE - 1];
    }
    out[i] = E[i];  // output row 0 = E_grid
    if (i == NE - 1) {
#pragma unroll
        for (int x = 0; x < NX; ++x) {
            out[(1 + x) * NE + i] = Fl[x] > 0.f ? Fl[x] : 0.f;
            wf[x * NE + i] = wlast * Fl[x];
            acc[x * NE + i] = 0.f;
        }
        return;
    }
#pragma unroll
    for (int x = 0; x < NX; ++x) {
        float s = SC[x * NE + i];
#pragma unroll
        for (int p = 0; p < NX; ++p)
            s += K[(size_t)(x * NX + p) * PL + (size_t)i * NE + (NE - 1)] *
                 (wlast * Fl[p] + srcl[p]);
        acc[x * NE + i] = s;
    }
}

// Per-block inverse, column-sliced: grid (NBLK, 3). Each WG computes 64 of the
// 192 columns of X = T^{-1}; columns are independent and column-private in LDS.
// 2 threads per column (even/odd jj split), same-wave shuffle combine.
__global__ __launch_bounds__(256) void k_tinv(const float* __restrict__ E,
                                              const float* __restrict__ R,
                                              const float* __restrict__ K,
                                              float* __restrict__ Gt) {
    __shared__ float Xs[BR][BS];        // 49152 B: Xs[row][local col]
    __shared__ float Kst[CHS][9][BS];   // 18432 B: staged K rows for 8 steps
    __shared__ float Binv[BS][9];
    __shared__ float wloc[BS];
    const size_t PL = (size_t)NE * NE;
    int b = blockIdx.x;
    int g = blockIdx.y;                 // column group 0..2
    int i0 = b * BS;
    int tid = threadIdx.x;
    float dy = dy_of(E);

    if (tid < BS) {
        int j = i0 + tid;
        wloc[tid] = (j < NE - 1) ? dy * E[j] : 0.f;
        int ii = tid, i = i0 + ii;
        float b00, b01, b02, b10, b11, b12, b20, b21, b22;
        if (i < NROWS) {
            float h = -0.5f * dy * E[i];
            size_t d = (size_t)i * NE + i;
            b00 = h * K[0 * PL + d] + R[0 * NE + i];
            b01 = h * K[1 * PL + d];
            b02 = h * K[2 * PL + d];
            b10 = h * K[3 * PL + d];
            b11 = h * K[4 * PL + d] + R[1 * NE + i];
            b12 = h * K[5 * PL + d];
            b20 = h * K[6 * PL + d];
            b21 = h * K[7 * PL + d];
            b22 = h * K[8 * PL + d] + R[2 * NE + i];
        } else {
            b00 = 1.f; b01 = 0.f; b02 = 0.f;
            b10 = 0.f; b11 = 1.f; b12 = 0.f;
            b20 = 0.f; b21 = 0.f; b22 = 1.f;
        }
        float C00 = b11 * b22 - b12 * b21;
        float C01 = -(b10 * b22 - b12 * b20);
        float C02 = b10 * b21 - b11 * b20;
        float C10 = -(b01 * b22 - b02 * b21);
        float C11 = b00 * b22 - b02 * b20;
        float C12 = -(b00 * b21 - b01 * b20);
        float C20 = b01 * b12 - b02 * b11;
        float C21 = -(b00 * b12 - b02 * b10);
        float C22 = b00 * b11 - b01 * b10;
        float inv = 1.f / (b00 * C00 + b01 * C01 + b02 * C02);
        Binv[ii][0] = C00 * inv; Binv[ii][1] = C10 * inv; Binv[ii][2] = C20 * inv;
        Binv[ii][3] = C01 * inv; Binv[ii][4] = C11 * inv; Binv[ii][5] = C21 * inv;
        Binv[ii][6] = C02 * inv; Binv[ii][7] = C12 * inv; Binv[ii][8] = C22 * inv;
    }
    __syncthreads();

    // T14 reg staging: q = (s*9+pair)*64 + jj; each wave's 64 q's are one
    // contiguous 256B global segment (coalesced).
    float rg[PERTH];
#pragma unroll
    for (int k = 0; k < PERTH; ++k) {
        int q = tid + k * 256;
        int s = q / (9 * BS);
        int pair = (q / BS) % 9;
        int jj = q & (BS - 1);
        int row = i0 + (BS - 1) - s;   // chunk 0
        rg[k] = K[(size_t)pair * PL + (size_t)row * NE + (i0 + jj)];
    }

    for (int c = 0; c < NCH; ++c) {
        if (c > 0) __syncthreads();     // prev chunk's compute done -> safe to overwrite Kst
#pragma unroll
        for (int k = 0; k < PERTH; ++k)
            ((float*)Kst)[tid + k * 256] = rg[k];
        __syncthreads();                // Kst visible
        if (c + 1 < NCH) {              // issue next chunk's loads; latency hides under compute
#pragma unroll
            for (int k = 0; k < PERTH; ++k) {
                int q = tid + k * 256;
                int s = q / (9 * BS);
                int pair = (q / BS) % 9;
                int jj = q & (BS - 1);
                int row = i0 + (BS - 1) - ((c + 1) * CHS + s);
                rg[k] = K[(size_t)pair * PL + (size_t)row * NE + (i0 + jj)];
            }
        }
        if (tid < 128) {
            int cloc = tid >> 1, sub = tid & 1;
            int colb = g * BS + cloc;   // block-local column 0..191
            for (int s = 0; s < CHS; ++s) {
                int ii = (BS - 1) - (c * CHS + s);
                int i = i0 + ii;
                float v0 = 0.f, v1 = 0.f, v2 = 0.f;
                if (sub == 0) {
                    v0 = (colb == 3 * ii + 0) ? 1.f : 0.f;
                    v1 = (colb == 3 * ii + 1) ? 1.f : 0.f;
                    v2 = (colb == 3 * ii + 2) ? 1.f : 0.f;
                }
                if (i < NROWS) {
                    for (int jj = ii + 1 + sub; jj < BS; jj += 2) {
                        float w = wloc[jj];
                        float x0 = Xs[3 * jj + 0][cloc];
                        float x1 = Xs[3 * jj + 1][cloc];
                        float x2 = Xs[3 * jj + 2][cloc];
                        v0 += w * (Kst[s][0][jj] * x0 + Kst[s][1][jj] * x1 + Kst[s][2][jj] * x2);
                        v1 += w * (Kst[s][3][jj] * x0 + Kst[s][4][jj] * x1 + Kst[s][5][jj] * x2);
                        v2 += w * (Kst[s][6][jj] * x0 + Kst[s][7][jj] * x1 + Kst[s][8][jj] * x2);
                    }
                }
                v0 += __shfl_xor(v0, 1);
                v1 += __shfl_xor(v1, 1);
                v2 += __shfl_xor(v2, 1);
                if (sub == 0) {
                    float f0, f1, f2;
                    if (i < NROWS) {
                        const float* bv = Binv[ii];
                        f0 = bv[0] * v0 + bv[1] * v1 + bv[2] * v2;
                        f1 = bv[3] * v0 + bv[4] * v1 + bv[5] * v2;
                        f2 = bv[6] * v0 + bv[7] * v1 + bv[8] * v2;
                    } else {
                        f0 = v0; f1 = v1; f2 = v2;  // identity row (pad)
                    }
                    Xs[3 * ii + 0][cloc] = f0;
                    Xs[3 * ii + 1][cloc] = f1;
                    Xs[3 * ii + 2][cloc] = f2;
                    float* gp = Gt + ((size_t)b * BR + colb) * BR + 3 * ii;
                    gp[0] = f0; gp[1] = f1; gp[2] = f2;
                }
                __builtin_amdgcn_wave_barrier();  // order LDS write->read across steps
            }
        }
    }
}

// One stage: gemv WGs (far-panel rank update into acc) + one apply WG that
// spin-waits on a device-scope counter, then F_blk = G_b @ a_blk.
__global__ __launch_bounds__(256) void k_stage(const float* __restrict__ E,
                                               const float* __restrict__ K,
                                               const float* __restrict__ Gt,
                                               float* __restrict__ acc,
                                               float* __restrict__ wf,
                                               float* __restrict__ out,
                                               int* __restrict__ cnt,
                                               int b, int nGemv, int chunks) {
    const size_t PL = (size_t)NE * NE;
    int i0 = b * BS;
    int tid = threadIdx.x;
    int bid = blockIdx.x;

    if (bid < nGemv) {
        int rowIdx = bid & (BS - 1);
        int ck = bid >> 6;
        int i = i0 + rowIdx;
        int jlo = i0 + BS, jhi = NROWS;
        int len = jhi - jlo;
        int per = (len + chunks - 1) / chunks;
        int lo = jlo + ck * per;
        int hi = min(lo + per, jhi);
        float s0 = 0.f, s1 = 0.f, s2 = 0.f;
        if (i < NROWS) {
            for (int j = lo + tid; j < hi; j += 256) {
                float w0 = wf[0 * NE + j], w1 = wf[1 * NE + j], w2 = wf[2 * NE + j];
                const float* Kb = K + (size_t)i * NE + j;
                s0 += Kb[0 * PL] * w0 + Kb[1 * PL] * w1 + Kb[2 * PL] * w2;
                s1 += Kb[3 * PL] * w0 + Kb[4 * PL] * w1 + Kb[5 * PL] * w2;
                s2 += Kb[6 * PL] * w0 + Kb[7 * PL] * w1 + Kb[8 * PL] * w2;
            }
        }
#pragma unroll
        for (int m = 32; m; m >>= 1) {
            s0 += __shfl_xor(s0, m);
            s1 += __shfl_xor(s1, m);
            s2 += __shfl_xor(s2, m);
        }
        __shared__ float red[4][3];
        int wv = tid >> 6;
        if ((tid & 63) == 0) { red[wv][0] = s0; red[wv][1] = s1; red[wv][2] = s2; }
        __syncthreads();
        if (tid == 0) {
            if (i < NROWS) {
                atomicAdd(&acc[0 * NE + i], red[0][0] + red[1][0] + red[2][0] + red[3][0]);
                atomicAdd(&acc[1 * NE + i], red[0][1] + red[1][1] + red[2][1] + red[3][1]);
                atomicAdd(&acc[2 * NE + i], red[0][2] + red[1][2] + red[2][2] + red[3][2]);
            }
            __threadfence();
            __hip_atomic_fetch_add(&cnt[b], 1, __ATOMIC_RELEASE, __HIP_MEMORY_SCOPE_AGENT);
        }
    } else {
        __shared__ float aL[BR];
        if (tid == 0 && nGemv > 0) {
            while (__hip_atomic_load(&cnt[b], __ATOMIC_ACQUIRE, __HIP_MEMORY_SCOPE_AGENT) < nGemv)
                __builtin_amdgcn_s_sleep(2);
        }
        __syncthreads();
        if (tid < BR) {
            int jj = tid / 3, p = tid % 3;
            int j = i0 + jj;
            aL[tid] = (j < NROWS) ? acc[p * NE + j] : 0.f;
        }
        __syncthreads();
        if (tid < BR) {
            const float* gcol = Gt + (size_t)b * BR * BR;  // Gt[c][rho] = gcol[c*BR+rho]
            float s = 0.f;
#pragma unroll 4
            for (int cc = 0; cc < BR; ++cc)
                s += gcol[(size_t)cc * BR + tid] * aL[cc];  // coalesced across tid
            int ii = tid / 3, x = tid % 3;
            int i = i0 + ii;
            if (i < NROWS) {
                float dy = dy_of(E);
                out[(1 + x) * NE + i] = s > 0.f ? s : 0.f;
                wf[x * NE + i] = dy * E[i] * s;
            }
        }
    }
}

extern "C" void kernel_launch(void* const* d_in, const int* in_sizes, int n_in,
                              void* d_out, int out_size, void* d_ws, size_t ws_size,
                              hipStream_t stream) {
    const float* E = (const float*)d_in[0];
    const float* R = (const float*)d_in[1];
    const float* K = (const float*)d_in[2];
    const float* S0 = (const float*)d_in[3];
    const float* SC = (const float*)d_in[4];
    float* out = (float*)d_out;
    float* wf = (float*)d_ws;
    float* acc = wf + NX * NE;
    float* Gt = acc + NX * NE;
    int* cnt = (int*)(Gt + (size_t)NBLK * BR * BR);

    k_init<<<(NE + 255) / 256, 256, 0, stream>>>(E, R, K, S0, SC, out, wf, acc, cnt);
    k_tinv<<<dim3(NBLK, 3), 256, 0, stream>>>(E, R, K, Gt);

    for (int b = NBLK - 1; b >= 0; --b) {
        int i0 = b * BS;
        int len = NROWS - (i0 + BS);
        int chunks = (len > 0) ? ((len + 511) / 512 < 8 ? ((len + 511) / 512) : 8) : 0;
        if (chunks < 1 && len > 0) chunks = 1;
        int nGemv = chunks * BS;
        k_stage<<<nGemv + 1, 256, 0, stream>>>(E, K, Gt, acc, wf, out, cnt, b, nGemv, chunks);
    }
}

// Round 5
// 730.246 us; speedup vs baseline: 1.0746x; 1.0746x over previous
//
#include <hip/hip_runtime.h>
#include <cstddef>
#include <cstdint>

#define NE 2048
#define NX 3
#define NROWS (NE - 1)               // rows solved by back-substitution: i = 0..2046
#define BS 64                        // block size (rows per block)
#define BR (3 * BS)                  // 192
#define NBLK 32
#define NCH 8                        // K-staging chunks in k_tinv
#define CHS 8                        // steps per chunk (NCH*CHS == BS)
#define CHQ (CHS * 9 * BS)           // 4608 floats per chunk
#define PERTH (CHQ / 256)            // 18 floats per thread

// ws layout (floats):
//   wf  [3*NE]        @ 0          wf[p][j] = w_j * F[p][j]
//   acc [3*NE]        @ 3*NE       running RHS accumulator
//   Gt  [NBLK*BR*BR]  @ 6*NE       per-block T^{-1}, transposed: Gt[b][col][row]
//   cnt [NBLK] ints   @ end        per-stage ticket counters (zeroed by k_init)

static __device__ __forceinline__ float dy_of(const float* E) {
    return logf(E[NE - 1] / E[0]) / (float)(NE - 1);
}

__global__ void k_init(const float* __restrict__ E, const float* __restrict__ R,
                       const float* __restrict__ K, const float* __restrict__ S0,
                       const float* __restrict__ SC,
                       float* __restrict__ out, float* __restrict__ wf,
                       float* __restrict__ acc, int* __restrict__ cnt) {
    int i = blockIdx.x * blockDim.x + threadIdx.x;
    if (blockIdx.x == 0 && threadIdx.x < NBLK) cnt[threadIdx.x] = 0;
    if (i >= NE) return;
    const size_t PL = (size_t)NE * NE;
    float dy = dy_of(E);
    float wlast = 0.5f * dy * E[NE - 1];
    float srcl[NX], Fl[NX];
#pragma unroll
    for (int p = 0; p < NX; ++p) srcl[p] = S0[p] / R[p * NE + NE - 1];
#pragma unroll
    for (int x = 0; x < NX; ++x) {
        float s = SC[x * NE + NE - 1];
#pragma unroll
        for (int p = 0; p < NX; ++p)
            s += K[(size_t)(x * NX + p) * PL + (size_t)(NE - 1) * NE + (NE - 1)] * srcl[p];
        Fl[x] = s / R[x * NE + NE - 1];
    }
    out[i] = E[i];  // output row 0 = E_grid
    if (i == NE - 1) {
#pragma unroll
        for (int x = 0; x < NX; ++x) {
            out[(1 + x) * NE + i] = Fl[x] > 0.f ? Fl[x] : 0.f;
            wf[x * NE + i] = wlast * Fl[x];
            acc[x * NE + i] = 0.f;
        }
        return;
    }
#pragma unroll
    for (int x = 0; x < NX; ++x) {
        float s = SC[x * NE + i];
#pragma unroll
        for (int p = 0; p < NX; ++p)
            s += K[(size_t)(x * NX + p) * PL + (size_t)i * NE + (NE - 1)] *
                 (wlast * Fl[p] + srcl[p]);
        acc[x * NE + i] = s;
    }
}

// Per-block inverse, column-sliced (R3-proven version, unchanged).
__global__ __launch_bounds__(256) void k_tinv(const float* __restrict__ E,
                                              const float* __restrict__ R,
                                              const float* __restrict__ K,
                                              float* __restrict__ Gt) {
    __shared__ float Xs[BR][BS];        // 49152 B: Xs[row][local col]
    __shared__ float Kst[CHS][9][BS];   // 18432 B
    __shared__ float Binv[BS][9];
    __shared__ float wloc[BS];
    const size_t PL = (size_t)NE * NE;
    int b = blockIdx.x;
    int g = blockIdx.y;                 // column group 0..2
    int i0 = b * BS;
    int tid = threadIdx.x;
    float dy = dy_of(E);

    if (tid < BS) {
        int j = i0 + tid;
        wloc[tid] = (j < NE - 1) ? dy * E[j] : 0.f;
        int ii = tid, i = i0 + ii;
        float b00, b01, b02, b10, b11, b12, b20, b21, b22;
        if (i < NROWS) {
            float h = -0.5f * dy * E[i];
            size_t d = (size_t)i * NE + i;
            b00 = h * K[0 * PL + d] + R[0 * NE + i];
            b01 = h * K[1 * PL + d];
            b02 = h * K[2 * PL + d];
            b10 = h * K[3 * PL + d];
            b11 = h * K[4 * PL + d] + R[1 * NE + i];
            b12 = h * K[5 * PL + d];
            b20 = h * K[6 * PL + d];
            b21 = h * K[7 * PL + d];
            b22 = h * K[8 * PL + d] + R[2 * NE + i];
        } else {
            b00 = 1.f; b01 = 0.f; b02 = 0.f;
            b10 = 0.f; b11 = 1.f; b12 = 0.f;
            b20 = 0.f; b21 = 0.f; b22 = 1.f;
        }
        float C00 = b11 * b22 - b12 * b21;
        float C01 = -(b10 * b22 - b12 * b20);
        float C02 = b10 * b21 - b11 * b20;
        float C10 = -(b01 * b22 - b02 * b21);
        float C11 = b00 * b22 - b02 * b20;
        float C12 = -(b00 * b21 - b01 * b20);
        float C20 = b01 * b12 - b02 * b11;
        float C21 = -(b00 * b12 - b02 * b10);
        float C22 = b00 * b11 - b01 * b10;
        float inv = 1.f / (b00 * C00 + b01 * C01 + b02 * C02);
        Binv[ii][0] = C00 * inv; Binv[ii][1] = C10 * inv; Binv[ii][2] = C20 * inv;
        Binv[ii][3] = C01 * inv; Binv[ii][4] = C11 * inv; Binv[ii][5] = C21 * inv;
        Binv[ii][6] = C02 * inv; Binv[ii][7] = C12 * inv; Binv[ii][8] = C22 * inv;
    }
    __syncthreads();

    float rg[PERTH];
#pragma unroll
    for (int k = 0; k < PERTH; ++k) {
        int q = tid + k * 256;
        int s = q / (9 * BS);
        int pair = (q / BS) % 9;
        int jj = q & (BS - 1);
        int row = i0 + (BS - 1) - s;
        rg[k] = K[(size_t)pair * PL + (size_t)row * NE + (i0 + jj)];
    }

    for (int c = 0; c < NCH; ++c) {
        if (c > 0) __syncthreads();
#pragma unroll
        for (int k = 0; k < PERTH; ++k)
            ((float*)Kst)[tid + k * 256] = rg[k];
        __syncthreads();
        if (c + 1 < NCH) {
#pragma unroll
            for (int k = 0; k < PERTH; ++k) {
                int q = tid + k * 256;
                int s = q / (9 * BS);
                int pair = (q / BS) % 9;
                int jj = q & (BS - 1);
                int row = i0 + (BS - 1) - ((c + 1) * CHS + s);
                rg[k] = K[(size_t)pair * PL + (size_t)row * NE + (i0 + jj)];
            }
        }
        if (tid < 128) {
            int cloc = tid >> 1, sub = tid & 1;
            int colb = g * BS + cloc;
            for (int s = 0; s < CHS; ++s) {
                int ii = (BS - 1) - (c * CHS + s);
                int i = i0 + ii;
                float v0 = 0.f, v1 = 0.f, v2 = 0.f;
                if (sub == 0) {
                    v0 = (colb == 3 * ii + 0) ? 1.f : 0.f;
                    v1 = (colb == 3 * ii + 1) ? 1.f : 0.f;
                    v2 = (colb == 3 * ii + 2) ? 1.f : 0.f;
                }
                if (i < NROWS) {
                    for (int jj = ii + 1 + sub; jj < BS; jj += 2) {
                        float w = wloc[jj];
                        float x0 = Xs[3 * jj + 0][cloc];
                        float x1 = Xs[3 * jj + 1][cloc];
                        float x2 = Xs[3 * jj + 2][cloc];
                        v0 += w * (Kst[s][0][jj] * x0 + Kst[s][1][jj] * x1 + Kst[s][2][jj] * x2);
                        v1 += w * (Kst[s][3][jj] * x0 + Kst[s][4][jj] * x1 + Kst[s][5][jj] * x2);
                        v2 += w * (Kst[s][6][jj] * x0 + Kst[s][7][jj] * x1 + Kst[s][8][jj] * x2);
                    }
                }
                v0 += __shfl_xor(v0, 1);
                v1 += __shfl_xor(v1, 1);
                v2 += __shfl_xor(v2, 1);
                if (sub == 0) {
                    float f0, f1, f2;
                    if (i < NROWS) {
                        const float* bv = Binv[ii];
                        f0 = bv[0] * v0 + bv[1] * v1 + bv[2] * v2;
                        f1 = bv[3] * v0 + bv[4] * v1 + bv[5] * v2;
                        f2 = bv[6] * v0 + bv[7] * v1 + bv[8] * v2;
                    } else {
                        f0 = v0; f1 = v1; f2 = v2;
                    }
                    Xs[3 * ii + 0][cloc] = f0;
                    Xs[3 * ii + 1][cloc] = f1;
                    Xs[3 * ii + 2][cloc] = f2;
                    float* gp = Gt + ((size_t)b * BR + colb) * BR + 3 * ii;
                    gp[0] = f0; gp[1] = f1; gp[2] = f2;
                }
                __builtin_amdgcn_wave_barrier();
            }
        }
    }
}

// Fused stage: far-panel gemv WGs + "last ticket does the apply" epilogue.
// No WG ever waits on another -> deadlock-impossible by construction.
__global__ __launch_bounds__(256) void k_stage(const float* __restrict__ E,
                                               const float* __restrict__ K,
                                               const float* __restrict__ Gt,
                                               float* __restrict__ acc,
                                               float* __restrict__ wf,
                                               float* __restrict__ out,
                                               int* __restrict__ cnt,
                                               int b, int nGemv, int chunks) {
    const size_t PL = (size_t)NE * NE;
    int i0 = b * BS;
    int tid = threadIdx.x;
    int bid = blockIdx.x;
    __shared__ int win;

    if (nGemv > 0) {
        int rowIdx = bid & (BS - 1);
        int ck = bid >> 6;
        int i = i0 + rowIdx;
        int jlo = i0 + BS, jhi = NROWS;
        int len = jhi - jlo;
        int per = (len + chunks - 1) / chunks;
        int lo = jlo + ck * per;
        int hi = min(lo + per, jhi);
        float s0 = 0.f, s1 = 0.f, s2 = 0.f;
        if (i < NROWS) {
            for (int j = lo + tid; j < hi; j += 256) {
                float w0 = wf[0 * NE + j], w1 = wf[1 * NE + j], w2 = wf[2 * NE + j];
                const float* Kb = K + (size_t)i * NE + j;
                s0 += Kb[0 * PL] * w0 + Kb[1 * PL] * w1 + Kb[2 * PL] * w2;
                s1 += Kb[3 * PL] * w0 + Kb[4 * PL] * w1 + Kb[5 * PL] * w2;
                s2 += Kb[6 * PL] * w0 + Kb[7 * PL] * w1 + Kb[8 * PL] * w2;
            }
        }
#pragma unroll
        for (int m = 32; m; m >>= 1) {
            s0 += __shfl_xor(s0, m);
            s1 += __shfl_xor(s1, m);
            s2 += __shfl_xor(s2, m);
        }
        __shared__ float red[4][3];
        int wv = tid >> 6;
        if ((tid & 63) == 0) { red[wv][0] = s0; red[wv][1] = s1; red[wv][2] = s2; }
        __syncthreads();
        if (tid == 0 && i < NROWS) {
            atomicAdd(&acc[0 * NE + i], red[0][0] + red[1][0] + red[2][0] + red[3][0]);
            atomicAdd(&acc[1 * NE + i], red[0][1] + red[1][1] + red[2][1] + red[3][1]);
            atomicAdd(&acc[2 * NE + i], red[0][2] + red[1][2] + red[2][2] + red[3][2]);
        }
        // __syncthreads() emits s_waitcnt vmcnt(0) first -> this WG's RMWs are
        // globally performed before the ticket below.
        __syncthreads();
        if (tid == 0) {
            int ret = __hip_atomic_fetch_add(&cnt[b], 1, __ATOMIC_ACQ_REL,
                                             __HIP_MEMORY_SCOPE_AGENT);
            win = (ret == nGemv - 1) ? 1 : 0;
        }
        __syncthreads();
        if (!win) return;
        __syncthreads();  // re-converge before the apply's shared-mem phase
    }

    // Apply: F_blk = Gt[b] @ acc_blk (winner WG only, or the sole WG if nGemv==0)
    __shared__ float aL[BR];
    if (tid < BR) {
        int jj = tid / 3, p = tid % 3;
        int j = i0 + jj;
        aL[tid] = (j < NROWS)
            ? __hip_atomic_load(&acc[p * NE + j], __ATOMIC_RELAXED, __HIP_MEMORY_SCOPE_AGENT)
            : 0.f;
    }
    __syncthreads();
    if (tid < BR) {
        const float* gcol = Gt + (size_t)b * BR * BR;  // Gt[c][r] = gcol[c*BR+r]
        float s = 0.f;
#pragma unroll 4
        for (int cc = 0; cc < BR; ++cc)
            s += gcol[(size_t)cc * BR + tid] * aL[cc];
        int ii = tid / 3, x = tid % 3;
        int i = i0 + ii;
        if (i < NROWS) {
            float dy = dy_of(E);
            out[(1 + x) * NE + i] = s > 0.f ? s : 0.f;
            wf[x * NE + i] = dy * E[i] * s;
        }
    }
}

extern "C" void kernel_launch(void* const* d_in, const int* in_sizes, int n_in,
                              void* d_out, int out_size, void* d_ws, size_t ws_size,
                              hipStream_t stream) {
    const float* E = (const float*)d_in[0];
    const float* R = (const float*)d_in[1];
    const float* K = (const float*)d_in[2];
    const float* S0 = (const float*)d_in[3];
    const float* SC = (const float*)d_in[4];
    float* out = (float*)d_out;
    float* wf = (float*)d_ws;
    float* acc = wf + NX * NE;
    float* Gt = acc + NX * NE;
    int* cnt = (int*)(Gt + (size_t)NBLK * BR * BR);

    k_init<<<(NE + 255) / 256, 256, 0, stream>>>(E, R, K, S0, SC, out, wf, acc, cnt);
    k_tinv<<<dim3(NBLK, 3), 256, 0, stream>>>(E, R, K, Gt);

    for (int b = NBLK - 1; b >= 0; --b) {
        int i0 = b * BS;
        int len = NROWS - (i0 + BS);
        int chunks = 0, nGemv = 0;
        if (len > 0) {
            chunks = len >> 9;           // ~512 columns per chunk
            if (chunks < 1) chunks = 1;
            if (chunks > 8) chunks = 8;
            nGemv = chunks * BS;
        }
        k_stage<<<(nGemv > 0 ? nGemv : 1), 256, 0, stream>>>(E, K, Gt, acc, wf, out,
                                                             cnt, b, nGemv, chunks);
    }
}